// Round 7
// baseline (363.756 us; speedup 1.0000x reference)
//
#include <hip/hip_runtime.h>
#include <hip/hip_bf16.h>

// Problem constants
#define NB   4
#define CIN  64
#define COUT 128
#define SDIM 512
#define DIM  48
#define SP   (DIM*DIM*DIM)   // 110592
#define TAPS 27
#define KTOT (CIN*TAPS)      // 1728

// ---- small-param layout (float offsets at base of ws) ----
#define WS_S1P 0                         // [NB*CIN]       1+scale
#define WS_SH  (WS_S1P + NB*CIN)         // [NB*CIN]       shift
#define WS_KM  (WS_SH + NB*CIN)          // [NB*CIN*TAPS]  kmod
// ---- fast path byte offsets ----
#define XPB_OFF   32768ull                        // padded mod x (bf16 channel-last), 64 MB
#define XPB_BYTES (4ull*125000ull*64ull*2ull)     // 64,000,000
#define WSBF_OFF  (XPB_OFF + XPB_BYTES)
#define WSBF_BYTES ((size_t)NB*27*8*128*8*2)      // 1,769,472

typedef __attribute__((ext_vector_type(4))) float  f32x4;
typedef __attribute__((ext_vector_type(8))) short  short8;
typedef __attribute__((ext_vector_type(8))) unsigned short u16x8;

__device__ __forceinline__ void gld16(const void* g, void* l) {
    __builtin_amdgcn_global_load_lds(
        (const __attribute__((address_space(1))) void*)g,
        (__attribute__((address_space(3))) void*)l, 16, 0, 0);
}

// ---------------------------------------------------------------------------
// Kernel A: style dot products. One wave per row.
// ---------------------------------------------------------------------------
__global__ void modparams_kernel(const float* __restrict__ style,
                                 const float* __restrict__ w_scale, const float* __restrict__ b_scale,
                                 const float* __restrict__ w_shift, const float* __restrict__ b_shift,
                                 const float* __restrict__ w_kmod,  const float* __restrict__ b_kmod,
                                 float* __restrict__ ws) {
    const int ROWS = 2 * CIN + CIN * TAPS;  // 1856
    int gwave = (blockIdx.x * blockDim.x + threadIdx.x) >> 6;
    int lane  = threadIdx.x & 63;
    if (gwave >= NB * ROWS) return;
    int b = gwave / ROWS;
    int r = gwave % ROWS;

    const float* srow = style + b * SDIM;
    const float* mrow;
    float bias, add = 0.f;
    float* dst;
    if (r < CIN) {
        mrow = w_scale + r * SDIM; bias = b_scale[r];
        dst = ws + WS_S1P + b * CIN + r; add = 1.f;          // store (1+scale)
    } else if (r < 2 * CIN) {
        int c = r - CIN;
        mrow = w_shift + c * SDIM; bias = b_shift[c];
        dst = ws + WS_SH + b * CIN + c;
    } else {
        int t = r - 2 * CIN;
        mrow = w_kmod + t * SDIM; bias = b_kmod[t];
        dst = ws + WS_KM + b * (CIN * TAPS) + t;
    }

    float acc = 0.f;
    for (int k = lane; k < SDIM; k += 64) acc += srow[k] * mrow[k];
    #pragma unroll
    for (int off = 32; off; off >>= 1) acc += __shfl_down(acc, off);
    if (lane == 0) *dst = acc + bias + add;
}

// ---------------------------------------------------------------------------
// WSBF2[(((b*27+tau)*8 + s)*128 + o)*8 + j] = bf16(weight[o, c=s*8+j, tau] *
//                                                  (1 + kmod[b, c, tau]))
// ---------------------------------------------------------------------------
__global__ void build_wsbf2_kernel(const float* __restrict__ weight, const float* __restrict__ ws,
                                   unsigned short* __restrict__ wsbf) {
    int d = blockIdx.x * blockDim.x + threadIdx.x;
    if (d >= NB * 27 * 8 * 128 * 8) return;
    int j   = d & 7;
    int o   = (d >> 3) & 127;
    int s   = (d >> 10) & 7;
    int rem = d >> 13;
    int tau = rem % 27;
    int b   = rem / 27;
    int c   = s * 8 + j;
    float wm = weight[(o * CIN + c) * TAPS + tau] * (1.f + ws[WS_KM + b * KTOT + c * TAPS + tau]);
    __hip_bfloat16 h = __float2bfloat16(wm);
    wsbf[d] = *(unsigned short*)&h;
}

// ---------------------------------------------------------------------------
// Pad + modulate + transpose to channel-last bf16: xpb[b][pz][py][px][c]
// ---------------------------------------------------------------------------
__global__ __launch_bounds__(256) void pad_kernel(const float* __restrict__ x,
                                                  const float* __restrict__ ws,
                                                  unsigned short* __restrict__ xpb) {
    __shared__ unsigned short lxm[48 * 72];   // [w][c], row stride 144B (16B-aligned)
    int bid = blockIdx.x;
    int py = bid % 50;
    int pz = (bid / 50) % 50;
    int b  = bid / 2500;
    int t = threadIdx.x;
    bool interior = (pz >= 1 && pz <= 48 && py >= 1 && py <= 48);
    if (interior) {
        int z = pz - 1, y = py - 1;
        const float* xr = x + (size_t)b * CIN * SP + (size_t)z * (DIM*DIM) + y * DIM;
        for (int i = t; i < 3072; i += 256) {
            int c = i / 48, w = i % 48;
            float v = xr[(size_t)c * SP + w];
            float m = v * ws[WS_S1P + b * CIN + c] + ws[WS_SH + b * CIN + c];
            __hip_bfloat16 h = __float2bfloat16(m);
            lxm[w * 72 + c] = *(unsigned short*)&h;
        }
    }
    __syncthreads();
    unsigned short* dst = xpb + (size_t)b * 8000000ull + ((size_t)pz * 2500 + py * 50) * 64;
    for (int i8 = t; i8 < 400; i8 += 256) {
        int w  = i8 >> 3;          // padded px
        int c8 = (i8 & 7) * 8;
        u16x8 v = {};
        if (interior && w >= 1 && w <= 48)
            v = *(const u16x8*)&lxm[(w - 1) * 72 + c8];
        *(u16x8*)(dst + i8 * 8) = v;
    }
}

// ---------------------------------------------------------------------------
// Conv v5: block = 128 couts x 256 positions (4z x 8y x 8x box), 512 thr.
// CHANNEL-SPLIT: two phases of 32 channels. Per phase: halo 6z x 10y x 10x x
// 32c bf16 in LDS (38.4 KB) staged once; 27 fully-unrolled taps; A weights in
// registers, double-buffered, prefetched one tap ahead. No barriers inside
// the tap loops -> waves free-run; small LDS -> 2-3 blocks/CU co-resident.
// ---------------------------------------------------------------------------
#define HALOPOS 600   // 6*10*10
#define BH_CHUNKS (HALOPOS * 4)   // 2400 16B-chunks per phase

#define STAGE(ph_) do {                                                        \
    _Pragma("unroll")                                                          \
    for (int it = 0; it < 5; ++it) {                                           \
        int i = it * 512 + t;                                                  \
        if (i < BH_CHUNKS) {                                                   \
            int slot = i & 3;                                                  \
            int pidx = i >> 2;                                                 \
            int hx = pidx % 10, hy = (pidx / 10) % 10, hz = pidx / 100;        \
            int srcslot = slot ^ (pidx & 3);                                   \
            const unsigned short* g = xb                                       \
                + ((size_t)((z0 + hz) * 2500 + (y0 + hy) * 50 + (x0 + hx))) * 64 \
                + (ph_) * 32 + srcslot * 8;                                    \
            gld16(g, &Bh[i * 8]);                                              \
        }                                                                      \
    }                                                                          \
} while (0)

// per-tap A prefetch: 4 x global_load_dwordx4 into short8 regs (one ch-phase)
#define LOADA(dst, ph_, tap_) do {                                             \
    _Pragma("unroll")                                                          \
    for (int j = 0; j < 4; ++j)                                                \
        dst[j] = *(const short8*)(wA + (size_t)(tap_) * 8192 +                 \
                                  (ph_) * 4096 + j * 128);                     \
} while (0)

#define COMPUTE(A, tap_) do {                                                  \
    const int kd_ = (tap_) / 9;                                                \
    const int r9_ = (tap_) - kd_ * 9;                                          \
    const int kh_ = r9_ / 3;                                                   \
    const int kw_ = r9_ - kh_ * 3;                                             \
    const int pb_ = pbase + kd_ * 100 + kh_ * 10 + kw_;                        \
    short8 bfr[4];                                                             \
    _Pragma("unroll")                                                          \
    for (int nf = 0; nf < 4; ++nf) {                                           \
        int pidx = pb_ + nf * 20;                                              \
        bfr[nf] = *(const short8*)&Bh[pidx * 32 + ((krow ^ (pidx & 3)) << 3)]; \
    }                                                                          \
    __builtin_amdgcn_s_setprio(1);                                             \
    _Pragma("unroll")                                                          \
    for (int mf = 0; mf < 4; ++mf) {                                           \
        _Pragma("unroll")                                                      \
        for (int nf = 0; nf < 4; ++nf)                                         \
            acc[mf][nf] = __builtin_amdgcn_mfma_f32_16x16x32_bf16(             \
                A[mf], bfr[nf], acc[mf][nf], 0, 0, 0);                         \
    }                                                                          \
    __builtin_amdgcn_s_setprio(0);                                             \
} while (0)

__global__ __launch_bounds__(512, 4) void conv_fast5_kernel(
    const unsigned short* __restrict__ xpb,
    const unsigned short* __restrict__ wsbf,
    const float* __restrict__ bias,
    float* __restrict__ out)
{
    __shared__ unsigned short Bh[HALOPOS * 32];   // 38,400 B

    const int t    = threadIdx.x;
    const int lane = t & 63;
    const int wid  = t >> 6;        // 0..7
    const int wz   = wid & 3;       // z-plane
    const int mh   = wid >> 2;      // M half (0/1)

    // XCD-aware bijective swizzle: 1728 = 8 * 216
    int bid0 = blockIdx.x;
    int bid  = (bid0 & 7) * 216 + (bid0 >> 3);
    int tile = bid % 432;
    int b    = bid / 432;
    int tx = tile % 6;
    int ty = (tile / 6) % 6;
    int tz = tile / 36;             // 0..11
    int x0 = tx * 8, y0 = ty * 8, z0 = tz * 4;

    const unsigned short* xb = xpb + (size_t)b * 8000000ull;
    const unsigned short* wb = wsbf + (size_t)b * (27 * 8 * 128 * 8);

    const int col  = lane & 15;
    const int krow = lane >> 4;   // 0..3
    const int cy   = col >> 3;    // 0..1
    const int cx   = col & 7;     // 0..7
    const int pbase = wz * 100 + cy * 10 + cx;

    // per-lane A base (shorts): slot = ph*4 + krow, o = mh*64 + mf*16 + col
    const unsigned short* wA = wb + (size_t)(krow * 128 + mh * 64 + col) * 8;

    f32x4 acc[4][4] = {};
    short8 a0[4], a1[4];

    LOADA(a0, 0, 0);
    STAGE(0);
    __syncthreads();   // halo ph0 staged (vmcnt drain)

    #pragma unroll
    for (int tap = 0; tap < 27; ++tap) {
        const int pfph  = (tap < 26) ? 0 : 1;
        const int pftap = (tap < 26) ? tap + 1 : 0;
        if (tap & 1) { LOADA(a0, pfph, pftap); COMPUTE(a1, tap); }
        else         { LOADA(a1, pfph, pftap); COMPUTE(a0, tap); }
    }

    __syncthreads();   // all reads of ph0 halo done
    STAGE(1);
    __syncthreads();   // halo ph1 staged

    #pragma unroll
    for (int tap = 0; tap < 27; ++tap) {
        // entering with (ph1, tap0) in a1
        if (tap & 1) { if (tap < 26) LOADA(a1, 1, tap + 1); COMPUTE(a0, tap); }
        else         { if (tap < 26) LOADA(a0, 1, tap + 1); COMPUTE(a1, tap); }
    }

    // ---- epilogue: + bias, store ----
    int z = z0 + wz;
    #pragma unroll
    for (int mf = 0; mf < 4; ++mf) {
        f32x4 bv = *(const f32x4*)&bias[mh * 64 + mf * 16 + krow * 4];
        #pragma unroll
        for (int nf = 0; nf < 4; ++nf) {
            int y = y0 + nf * 2 + cy;
            int xx = x0 + cx;
            size_t pbase2 = (size_t)z * (DIM * DIM) + (size_t)y * DIM + xx;
            f32x4 a = acc[mf][nf];
            #pragma unroll
            for (int r = 0; r < 4; ++r) {
                int o = mh * 64 + mf * 16 + krow * 4 + r;
                out[(size_t)(b * COUT + o) * SP + pbase2] = a[r] + bv[r];
            }
        }
    }
}

// ---------------------------------------------------------------------------
extern "C" void kernel_launch(void* const* d_in, const int* in_sizes, int n_in,
                              void* d_out, int out_size, void* d_ws, size_t ws_size,
                              hipStream_t stream) {
    const float* x       = (const float*)d_in[0];
    const float* style   = (const float*)d_in[1];
    const float* weight  = (const float*)d_in[2];
    const float* bias    = (const float*)d_in[3];
    const float* w_scale = (const float*)d_in[4];
    const float* b_scale = (const float*)d_in[5];
    const float* w_shift = (const float*)d_in[6];
    const float* b_shift = (const float*)d_in[7];
    const float* w_kmod  = (const float*)d_in[8];
    const float* b_kmod  = (const float*)d_in[9];
    float* out = (float*)d_out;
    float* ws  = (float*)d_ws;

    unsigned short* xpb  = (unsigned short*)((char*)d_ws + XPB_OFF);
    unsigned short* wsbf = (unsigned short*)((char*)d_ws + WSBF_OFF);

    {
        int waves = NB * (2 * CIN + CIN * TAPS);
        int blocks = (waves + 3) / 4;
        modparams_kernel<<<blocks, 256, 0, stream>>>(style, w_scale, b_scale,
                                                     w_shift, b_shift, w_kmod, b_kmod, ws);
    }
    {
        int n = NB * 27 * 8 * 128 * 8;
        build_wsbf2_kernel<<<(n + 255) / 256, 256, 0, stream>>>(weight, ws, wsbf);
    }
    {
        int blocks = NB * 50 * 50;
        pad_kernel<<<blocks, 256, 0, stream>>>(x, ws, xpb);
    }
    {
        int blocks = NB * 432;   // 1728
        conv_fast5_kernel<<<blocks, 512, 0, stream>>>(xpb, wsbf, bias, out);
    }
}

// Round 8
// 274.664 us; speedup vs baseline: 1.3244x; 1.3244x over previous
//
#include <hip/hip_runtime.h>
#include <hip/hip_bf16.h>

// Problem constants
#define NB   4
#define CIN  64
#define COUT 128
#define SDIM 512
#define DIM  48
#define SP   (DIM*DIM*DIM)   // 110592
#define TAPS 27
#define KTOT (CIN*TAPS)      // 1728

// ---- small-param layout (float offsets at base of ws) ----
#define WS_S1P 0                         // [NB*CIN]       1+scale
#define WS_SH  (WS_S1P + NB*CIN)         // [NB*CIN]       shift
#define WS_KM  (WS_SH + NB*CIN)          // [NB*CIN*TAPS]  kmod
// ---- fast path byte offsets ----
#define XPB_OFF   32768ull                        // padded mod x (bf16 channel-last), 64 MB
#define XPB_BYTES (4ull*125000ull*64ull*2ull)     // 64,000,000
#define WSBF_OFF  (XPB_OFF + XPB_BYTES)
#define WSBF_BYTES ((size_t)NB*27*8*128*8*2)      // 1,769,472

typedef __attribute__((ext_vector_type(4))) float  f32x4;
typedef __attribute__((ext_vector_type(8))) short  short8;
typedef __attribute__((ext_vector_type(8))) unsigned short u16x8;

__device__ __forceinline__ void gld16(const void* g, void* l) {
    __builtin_amdgcn_global_load_lds(
        (const __attribute__((address_space(1))) void*)g,
        (__attribute__((address_space(3))) void*)l, 16, 0, 0);
}

// ---------------------------------------------------------------------------
// Kernel A: style dot products. One wave per row.
// ---------------------------------------------------------------------------
__global__ void modparams_kernel(const float* __restrict__ style,
                                 const float* __restrict__ w_scale, const float* __restrict__ b_scale,
                                 const float* __restrict__ w_shift, const float* __restrict__ b_shift,
                                 const float* __restrict__ w_kmod,  const float* __restrict__ b_kmod,
                                 float* __restrict__ ws) {
    const int ROWS = 2 * CIN + CIN * TAPS;  // 1856
    int gwave = (blockIdx.x * blockDim.x + threadIdx.x) >> 6;
    int lane  = threadIdx.x & 63;
    if (gwave >= NB * ROWS) return;
    int b = gwave / ROWS;
    int r = gwave % ROWS;

    const float* srow = style + b * SDIM;
    const float* mrow;
    float bias, add = 0.f;
    float* dst;
    if (r < CIN) {
        mrow = w_scale + r * SDIM; bias = b_scale[r];
        dst = ws + WS_S1P + b * CIN + r; add = 1.f;          // store (1+scale)
    } else if (r < 2 * CIN) {
        int c = r - CIN;
        mrow = w_shift + c * SDIM; bias = b_shift[c];
        dst = ws + WS_SH + b * CIN + c;
    } else {
        int t = r - 2 * CIN;
        mrow = w_kmod + t * SDIM; bias = b_kmod[t];
        dst = ws + WS_KM + b * (CIN * TAPS) + t;
    }

    float acc = 0.f;
    for (int k = lane; k < SDIM; k += 64) acc += srow[k] * mrow[k];
    #pragma unroll
    for (int off = 32; off; off >>= 1) acc += __shfl_down(acc, off);
    if (lane == 0) *dst = acc + bias + add;
}

// ---------------------------------------------------------------------------
// WSBF2[(((b*27+tau)*8 + s)*128 + o)*8 + j] = bf16(weight[o, c=s*8+j, tau] *
//                                                  (1 + kmod[b, c, tau]))
// ---------------------------------------------------------------------------
__global__ void build_wsbf2_kernel(const float* __restrict__ weight, const float* __restrict__ ws,
                                   unsigned short* __restrict__ wsbf) {
    int d = blockIdx.x * blockDim.x + threadIdx.x;
    if (d >= NB * 27 * 8 * 128 * 8) return;
    int j   = d & 7;
    int o   = (d >> 3) & 127;
    int s   = (d >> 10) & 7;
    int rem = d >> 13;
    int tau = rem % 27;
    int b   = rem / 27;
    int c   = s * 8 + j;
    float wm = weight[(o * CIN + c) * TAPS + tau] * (1.f + ws[WS_KM + b * KTOT + c * TAPS + tau]);
    __hip_bfloat16 h = __float2bfloat16(wm);
    wsbf[d] = *(unsigned short*)&h;
}

// ---------------------------------------------------------------------------
// Pad + modulate + transpose to channel-last bf16: xpb[b][pz][py][px][c]
// ---------------------------------------------------------------------------
__global__ __launch_bounds__(256) void pad_kernel(const float* __restrict__ x,
                                                  const float* __restrict__ ws,
                                                  unsigned short* __restrict__ xpb) {
    __shared__ unsigned short lxm[48 * 72];   // [w][c], row stride 144B (16B-aligned)
    int bid = blockIdx.x;
    int py = bid % 50;
    int pz = (bid / 50) % 50;
    int b  = bid / 2500;
    int t = threadIdx.x;
    bool interior = (pz >= 1 && pz <= 48 && py >= 1 && py <= 48);
    if (interior) {
        int z = pz - 1, y = py - 1;
        const float* xr = x + (size_t)b * CIN * SP + (size_t)z * (DIM*DIM) + y * DIM;
        for (int i = t; i < 3072; i += 256) {
            int c = i / 48, w = i % 48;
            float v = xr[(size_t)c * SP + w];
            float m = v * ws[WS_S1P + b * CIN + c] + ws[WS_SH + b * CIN + c];
            __hip_bfloat16 h = __float2bfloat16(m);
            lxm[w * 72 + c] = *(unsigned short*)&h;
        }
    }
    __syncthreads();
    unsigned short* dst = xpb + (size_t)b * 8000000ull + ((size_t)pz * 2500 + py * 50) * 64;
    for (int i8 = t; i8 < 400; i8 += 256) {
        int w  = i8 >> 3;          // padded px
        int c8 = (i8 & 7) * 8;
        u16x8 v = {};
        if (interior && w >= 1 && w <= 48)
            v = *(const u16x8*)&lxm[(w - 1) * 72 + c8];
        *(u16x8*)(dst + i8 * 8) = v;
    }
}

// ---------------------------------------------------------------------------
// Conv v6: block = 128 couts x 128 positions (2z x 8y x 8x box), 256 thr.
// Wave (mh, wz): 64 couts x 64 positions (z-plane wz), 4x4 fragments.
// B halo 4z x 10y x 10x x 64c bf16 in LDS (51.2 KB), staged ONCE (swizzled)
// -> 3 blocks/CU co-resident. A weights in registers, double-buffered,
// prefetched one tap ahead from global (L2-hot). Tap loop FULLY UNROLLED;
// zero barriers inside it -> waves free-run.
// ---------------------------------------------------------------------------
#define HALOPOS 400            // 4*10*10
#define BH_CHUNKS (HALOPOS*8)  // 3200 16B-chunks

// per-tap A prefetch: 8 x global_load_dwordx4 into short8 regs [ch][mf]
#define LOADA(dst, tap_) do {                                                  \
    _Pragma("unroll")                                                          \
    for (int j = 0; j < 8; ++j)                                                \
        dst[j] = *(const short8*)(wA + (size_t)(tap_) * 8192 +                 \
                                  (j >> 2) * 4096 + (j & 3) * 128);            \
} while (0)

#define COMPUTE(A, tap_) do {                                                  \
    const int kd_ = (tap_) / 9;                                                \
    const int r9_ = (tap_) - kd_ * 9;                                          \
    const int kh_ = r9_ / 3;                                                   \
    const int kw_ = r9_ - kh_ * 3;                                             \
    const int pb_ = pbase + kd_ * 100 + kh_ * 10 + kw_;                        \
    _Pragma("unroll")                                                          \
    for (int ch = 0; ch < 2; ++ch) {                                           \
        short8 bfr[4];                                                         \
        _Pragma("unroll")                                                      \
        for (int nf = 0; nf < 4; ++nf) {                                       \
            int pidx = pb_ + nf * 20;                                          \
            bfr[nf] = *(const short8*)&Bh[pidx * 64 +                          \
                          (((ch * 4 + krow) ^ (pidx & 7)) * 8)];               \
        }                                                                      \
        __builtin_amdgcn_s_setprio(1);                                         \
        _Pragma("unroll")                                                      \
        for (int mf = 0; mf < 4; ++mf) {                                       \
            _Pragma("unroll")                                                  \
            for (int nf = 0; nf < 4; ++nf)                                     \
                acc[mf][nf] = __builtin_amdgcn_mfma_f32_16x16x32_bf16(         \
                    A[ch * 4 + mf], bfr[nf], acc[mf][nf], 0, 0, 0);            \
        }                                                                      \
        __builtin_amdgcn_s_setprio(0);                                         \
    }                                                                          \
} while (0)

__global__ __launch_bounds__(256, 3) void conv_fast6_kernel(
    const unsigned short* __restrict__ xpb,
    const unsigned short* __restrict__ wsbf,
    const float* __restrict__ bias,
    float* __restrict__ out)
{
    __shared__ unsigned short Bh[HALOPOS * 64];   // 51,200 B

    const int t    = threadIdx.x;
    const int lane = t & 63;
    const int wid  = t >> 6;        // 0..3
    const int wz   = wid & 1;       // z-plane
    const int mh   = wid >> 1;      // M half (0/1)

    // XCD-aware bijective swizzle: 3456 = 8 * 432
    int bid0 = blockIdx.x;
    int bid  = (bid0 & 7) * 432 + (bid0 >> 3);
    int tile = bid % 864;
    int b    = bid / 864;
    int tx = tile % 6;
    int ty = (tile / 6) % 6;
    int tz = tile / 36;             // 0..23
    int x0 = tx * 8, y0 = ty * 8, z0 = tz * 2;

    const unsigned short* xb = xpb + (size_t)b * 8000000ull;
    const unsigned short* wb = wsbf + (size_t)b * (27 * 8 * 128 * 8);

    // ---- stage B halo once (source-swizzled so linear LDS == swizzled layout)
    #pragma unroll
    for (int it = 0; it < 13; ++it) {
        int i = it * 256 + t;
        if (i < BH_CHUNKS) {
            int pidx = i >> 3;
            int slot = i & 7;
            int hx = pidx % 10;
            int hy = (pidx / 10) % 10;
            int hz = pidx / 100;
            int srcslot = slot ^ (pidx & 7);
            const unsigned short* g = xb
                + ((size_t)((z0 + hz) * 2500 + (y0 + hy) * 50 + (x0 + hx))) * 64
                + srcslot * 8;
            gld16(g, &Bh[i * 8]);
        }
    }

    const int col  = lane & 15;
    const int krow = lane >> 4;   // 0..3
    const int cy   = col >> 3;    // 0..1
    const int cx   = col & 7;     // 0..7
    const int pbase = wz * 100 + cy * 10 + cx;

    // per-lane A base (shorts): slot = ch*4 + krow, o = mh*64 + mf*16 + col
    const unsigned short* wA = wb + (size_t)(krow * 128 + mh * 64 + col) * 8;

    f32x4 acc[4][4] = {};
    short8 a0[8], a1[8];

    LOADA(a0, 0);
    __syncthreads();   // halo staged (vmcnt drain); the ONLY block-wide barrier

    #pragma unroll
    for (int tap = 0; tap < 27; ++tap) {
        if (tap < 26) {
            if (tap & 1) LOADA(a0, tap + 1);
            else         LOADA(a1, tap + 1);
        }
        if (tap & 1) COMPUTE(a1, tap);
        else         COMPUTE(a0, tap);
    }

    // ---- epilogue: + bias, store ----
    int z = z0 + wz;
    #pragma unroll
    for (int mf = 0; mf < 4; ++mf) {
        f32x4 bv = *(const f32x4*)&bias[mh * 64 + mf * 16 + krow * 4];
        #pragma unroll
        for (int nf = 0; nf < 4; ++nf) {
            int y = y0 + nf * 2 + cy;
            int xx = x0 + cx;
            size_t pbase2 = (size_t)z * (DIM * DIM) + (size_t)y * DIM + xx;
            f32x4 a = acc[mf][nf];
            #pragma unroll
            for (int r = 0; r < 4; ++r) {
                int o = mh * 64 + mf * 16 + krow * 4 + r;
                out[(size_t)(b * COUT + o) * SP + pbase2] = a[r] + bv[r];
            }
        }
    }
}

// ---------------------------------------------------------------------------
extern "C" void kernel_launch(void* const* d_in, const int* in_sizes, int n_in,
                              void* d_out, int out_size, void* d_ws, size_t ws_size,
                              hipStream_t stream) {
    const float* x       = (const float*)d_in[0];
    const float* style   = (const float*)d_in[1];
    const float* weight  = (const float*)d_in[2];
    const float* bias    = (const float*)d_in[3];
    const float* w_scale = (const float*)d_in[4];
    const float* b_scale = (const float*)d_in[5];
    const float* w_shift = (const float*)d_in[6];
    const float* b_shift = (const float*)d_in[7];
    const float* w_kmod  = (const float*)d_in[8];
    const float* b_kmod  = (const float*)d_in[9];
    float* out = (float*)d_out;
    float* ws  = (float*)d_ws;

    unsigned short* xpb  = (unsigned short*)((char*)d_ws + XPB_OFF);
    unsigned short* wsbf = (unsigned short*)((char*)d_ws + WSBF_OFF);

    {
        int waves = NB * (2 * CIN + CIN * TAPS);
        int blocks = (waves + 3) / 4;
        modparams_kernel<<<blocks, 256, 0, stream>>>(style, w_scale, b_scale,
                                                     w_shift, b_shift, w_kmod, b_kmod, ws);
    }
    {
        int n = NB * 27 * 8 * 128 * 8;
        build_wsbf2_kernel<<<(n + 255) / 256, 256, 0, stream>>>(weight, ws, wsbf);
    }
    {
        int blocks = NB * 50 * 50;
        pad_kernel<<<blocks, 256, 0, stream>>>(x, ws, xpb);
    }
    {
        int blocks = NB * 864;   // 3456
        conv_fast6_kernel<<<blocks, 256, 0, stream>>>(xpb, wsbf, bias, out);
    }
}

// Round 9
// 260.820 us; speedup vs baseline: 1.3947x; 1.0531x over previous
//
#include <hip/hip_runtime.h>
#include <hip/hip_bf16.h>

// Problem constants
#define NB   4
#define CIN  64
#define COUT 128
#define SDIM 512
#define DIM  48
#define SP   (DIM*DIM*DIM)   // 110592
#define TAPS 27
#define KTOT (CIN*TAPS)      // 1728

// ---- small-param layout (float offsets at base of ws) ----
#define WS_S1P 0                         // [NB*CIN]       1+scale
#define WS_SH  (WS_S1P + NB*CIN)         // [NB*CIN]       shift
#define WS_KM  (WS_SH + NB*CIN)          // [NB*CIN*TAPS]  kmod
// ---- fast path byte offsets ----
#define XPB_OFF   32768ull                        // padded mod x (bf16 channel-last), 64 MB
#define XPB_BYTES (4ull*125000ull*64ull*2ull)     // 64,000,000
#define WSBF_OFF  (XPB_OFF + XPB_BYTES)
#define WSBF_BYTES ((size_t)NB*27*8*128*8*2)      // 1,769,472

typedef __attribute__((ext_vector_type(4)))  float f32x4;
typedef __attribute__((ext_vector_type(16))) float f32x16;
typedef __attribute__((ext_vector_type(8)))  short short8;
typedef __attribute__((ext_vector_type(8)))  unsigned short u16x8;

__device__ __forceinline__ void gld16(const void* g, void* l) {
    __builtin_amdgcn_global_load_lds(
        (const __attribute__((address_space(1))) void*)g,
        (__attribute__((address_space(3))) void*)l, 16, 0, 0);
}

// ---------------------------------------------------------------------------
// Kernel A: style dot products. One wave per row.
// ---------------------------------------------------------------------------
__global__ void modparams_kernel(const float* __restrict__ style,
                                 const float* __restrict__ w_scale, const float* __restrict__ b_scale,
                                 const float* __restrict__ w_shift, const float* __restrict__ b_shift,
                                 const float* __restrict__ w_kmod,  const float* __restrict__ b_kmod,
                                 float* __restrict__ ws) {
    const int ROWS = 2 * CIN + CIN * TAPS;  // 1856
    int gwave = (blockIdx.x * blockDim.x + threadIdx.x) >> 6;
    int lane  = threadIdx.x & 63;
    if (gwave >= NB * ROWS) return;
    int b = gwave / ROWS;
    int r = gwave % ROWS;

    const float* srow = style + b * SDIM;
    const float* mrow;
    float bias, add = 0.f;
    float* dst;
    if (r < CIN) {
        mrow = w_scale + r * SDIM; bias = b_scale[r];
        dst = ws + WS_S1P + b * CIN + r; add = 1.f;          // store (1+scale)
    } else if (r < 2 * CIN) {
        int c = r - CIN;
        mrow = w_shift + c * SDIM; bias = b_shift[c];
        dst = ws + WS_SH + b * CIN + c;
    } else {
        int t = r - 2 * CIN;
        mrow = w_kmod + t * SDIM; bias = b_kmod[t];
        dst = ws + WS_KM + b * (CIN * TAPS) + t;
    }

    float acc = 0.f;
    for (int k = lane; k < SDIM; k += 64) acc += srow[k] * mrow[k];
    #pragma unroll
    for (int off = 32; off; off >>= 1) acc += __shfl_down(acc, off);
    if (lane == 0) *dst = acc + bias + add;
}

// ---------------------------------------------------------------------------
// WSBF2[(((b*27+tau)*8 + s)*128 + o)*8 + j] = bf16(weight[o, c=s*8+j, tau] *
//                                                  (1 + kmod[b, c, tau]))
// ---------------------------------------------------------------------------
__global__ void build_wsbf2_kernel(const float* __restrict__ weight, const float* __restrict__ ws,
                                   unsigned short* __restrict__ wsbf) {
    int d = blockIdx.x * blockDim.x + threadIdx.x;
    if (d >= NB * 27 * 8 * 128 * 8) return;
    int j   = d & 7;
    int o   = (d >> 3) & 127;
    int s   = (d >> 10) & 7;
    int rem = d >> 13;
    int tau = rem % 27;
    int b   = rem / 27;
    int c   = s * 8 + j;
    float wm = weight[(o * CIN + c) * TAPS + tau] * (1.f + ws[WS_KM + b * KTOT + c * TAPS + tau]);
    __hip_bfloat16 h = __float2bfloat16(wm);
    wsbf[d] = *(unsigned short*)&h;
}

// ---------------------------------------------------------------------------
// Pad + modulate + transpose to channel-last bf16: xpb[b][pz][py][px][c]
// ---------------------------------------------------------------------------
__global__ __launch_bounds__(256) void pad_kernel(const float* __restrict__ x,
                                                  const float* __restrict__ ws,
                                                  unsigned short* __restrict__ xpb) {
    __shared__ unsigned short lxm[48 * 72];   // [w][c], row stride 144B (16B-aligned)
    int bid = blockIdx.x;
    int py = bid % 50;
    int pz = (bid / 50) % 50;
    int b  = bid / 2500;
    int t = threadIdx.x;
    bool interior = (pz >= 1 && pz <= 48 && py >= 1 && py <= 48);
    if (interior) {
        int z = pz - 1, y = py - 1;
        const float* xr = x + (size_t)b * CIN * SP + (size_t)z * (DIM*DIM) + y * DIM;
        for (int i = t; i < 3072; i += 256) {
            int c = i / 48, w = i % 48;
            float v = xr[(size_t)c * SP + w];
            float m = v * ws[WS_S1P + b * CIN + c] + ws[WS_SH + b * CIN + c];
            __hip_bfloat16 h = __float2bfloat16(m);
            lxm[w * 72 + c] = *(unsigned short*)&h;
        }
    }
    __syncthreads();
    unsigned short* dst = xpb + (size_t)b * 8000000ull + ((size_t)pz * 2500 + py * 50) * 64;
    for (int i8 = t; i8 < 400; i8 += 256) {
        int w  = i8 >> 3;          // padded px
        int c8 = (i8 & 7) * 8;
        u16x8 v = {};
        if (interior && w >= 1 && w <= 48)
            v = *(const u16x8*)&lxm[(w - 1) * 72 + c8];
        *(u16x8*)(dst + i8 * 8) = v;
    }
}

// ---------------------------------------------------------------------------
// Conv v7: block = 128 couts x 256 positions (4z x 8y x 8x box), 512 thr.
// Wave (mh, wz): 64 couts x 64 positions (z-plane wz) via 2x2 tiles of
// mfma_f32_32x32x16_bf16 (4 K-steps of 16 ch per tap -> 16 MFMA/wave-tap).
// B halo 6z x 10y x 10x x 64c bf16 in LDS (76.8 KB), staged ONCE (swizzled).
// A weights in registers, double-buffered, prefetched one tap ahead.
// B fragments double-buffered at K-step granularity: ds_read of ks+1 issues
// before the MFMA burst of ks. ZERO barriers in the tap loop.
// Fragment layouts (ext. of verified 16x16x32 mapping):
//   A: lane l holds A[m=l&31][k=(l>>5)*8+j]   (8 consecutive channels)
//   B: lane l holds B[k=(l>>5)*8+j][n=l&31]
//   C: col=lane&31, row=(r&3)+8*(r>>2)+4*(lane>>5)
// ---------------------------------------------------------------------------
#define HALOPOS 600            // 6*10*10
#define BH_CHUNKS (HALOPOS*8)  // 4800 16B-chunks

// A prefetch for one tap: 8 frags [ks(4)][mt(2)], each 16B/lane, coalesced.
#define LOADA32(dst, tap_) do {                                                \
    _Pragma("unroll")                                                          \
    for (int q = 0; q < 8; ++q)                                                \
        dst[q] = *(const short8*)(wA + (size_t)(tap_) * 8192 +                 \
                                  (q >> 1) * 2048 + (q & 1) * 256);            \
} while (0)

// B frags for one K-step ks: 2 Ntiles
#define LOADB(dst, tap_, ks_) do {                                             \
    const int kd_ = (tap_) / 9;                                                \
    const int kh_ = ((tap_) / 3) % 3;                                          \
    const int kw_ = (tap_) % 3;                                                \
    _Pragma("unroll")                                                          \
    for (int nt = 0; nt < 2; ++nt) {                                           \
        int pidx = pbase + kd_ * 100 + kh_ * 10 + kw_ + nt * 40;               \
        dst[nt] = *(const short8*)&Bh[pidx * 64 +                              \
                      ((((ks_) * 2 + hi) ^ (pidx & 7)) << 3)];                 \
    }                                                                          \
} while (0)

#define MFMA4(A, ks_, bb) do {                                                 \
    __builtin_amdgcn_s_setprio(1);                                             \
    _Pragma("unroll")                                                          \
    for (int mt = 0; mt < 2; ++mt) {                                           \
        _Pragma("unroll")                                                      \
        for (int nt = 0; nt < 2; ++nt)                                         \
            acc[mt][nt] = __builtin_amdgcn_mfma_f32_32x32x16_bf16(             \
                A[(ks_) * 2 + mt], bb[nt], acc[mt][nt], 0, 0, 0);              \
    }                                                                          \
    __builtin_amdgcn_s_setprio(0);                                             \
} while (0)

// one tap: A for t+1 prefetches early; B reads roll one K-step ahead
#define TAPBODY(Acur, Anxt, t_) do {                                           \
    if ((t_) < 26) LOADA32(Anxt, (t_) + 1);                                    \
    LOADB(b1, (t_), 1);                                                        \
    MFMA4(Acur, 0, b0);                                                        \
    LOADB(b0, (t_), 2);                                                        \
    MFMA4(Acur, 1, b1);                                                        \
    LOADB(b1, (t_), 3);                                                        \
    MFMA4(Acur, 2, b0);                                                        \
    if ((t_) < 26) LOADB(b0, (t_) + 1, 0);                                     \
    MFMA4(Acur, 3, b1);                                                        \
} while (0)

__global__ __launch_bounds__(512, 2) void conv_fast7_kernel(
    const unsigned short* __restrict__ xpb,
    const unsigned short* __restrict__ wsbf,
    const float* __restrict__ bias,
    float* __restrict__ out)
{
    __shared__ unsigned short Bh[HALOPOS * 64];   // 76,800 B

    const int t    = threadIdx.x;
    const int lane = t & 63;
    const int wid  = t >> 6;        // 0..7
    const int wz   = wid & 3;       // z-plane
    const int mh   = wid >> 2;      // M half (0/1)

    // XCD-aware bijective swizzle: 1728 = 8 * 216
    int bid0 = blockIdx.x;
    int bid  = (bid0 & 7) * 216 + (bid0 >> 3);
    int tile = bid % 432;
    int b    = bid / 432;
    int tx = tile % 6;
    int ty = (tile / 6) % 6;
    int tz = tile / 36;             // 0..11
    int x0 = tx * 8, y0 = ty * 8, z0 = tz * 4;

    const unsigned short* xb = xpb + (size_t)b * 8000000ull;
    const unsigned short* wb = wsbf + (size_t)b * (27 * 8 * 128 * 8);

    // ---- stage B halo once (source-swizzled so linear LDS == swizzled layout)
    #pragma unroll
    for (int it = 0; it < 10; ++it) {
        int i = it * 512 + t;
        if (i < BH_CHUNKS) {
            int pidx = i >> 3;
            int slot = i & 7;
            int hx = pidx % 10;
            int hy = (pidx / 10) % 10;
            int hz = pidx / 100;
            int srcslot = slot ^ (pidx & 7);
            const unsigned short* g = xb
                + ((size_t)((z0 + hz) * 2500 + (y0 + hy) * 50 + (x0 + hx))) * 64
                + srcslot * 8;
            gld16(g, &Bh[i * 8]);
        }
    }

    const int hi   = lane >> 5;     // k-half
    const int n    = lane & 31;     // B column / C column
    const int cy4  = (n >> 3) & 3;  // 0..3
    const int cx   = n & 7;         // 0..7
    const int pbase = wz * 100 + cy4 * 10 + cx;

    // per-lane A base (shorts): s-slot = ks*2 + hi, o = mh*64 + mt*32 + (lane&31)
    const unsigned short* wA = wb + (size_t)(hi * 1024 + (mh * 64 + n) * 8);

    f32x16 acc[2][2] = {};
    short8 aA[8], aB[8], b0[2], b1[2];

    LOADA32(aA, 0);
    __syncthreads();   // halo staged (vmcnt drain); the ONLY block-wide barrier

    LOADB(b0, 0, 0);
    #pragma unroll
    for (int tp = 0; tp < 26; tp += 2) {
        TAPBODY(aA, aB, tp);
        TAPBODY(aB, aA, tp + 1);
    }
    TAPBODY(aA, aB, 26);

    // ---- epilogue: + bias, store ----
    int z  = z0 + wz;
    int xx = x0 + cx;
    #pragma unroll
    for (int mt = 0; mt < 2; ++mt) {
        #pragma unroll
        for (int q = 0; q < 4; ++q) {
            int ob = mh * 64 + mt * 32 + q * 8 + hi * 4;
            f32x4 bv = *(const f32x4*)&bias[ob];
            #pragma unroll
            for (int nt = 0; nt < 2; ++nt) {
                int y = y0 + nt * 4 + cy4;
                size_t p = (size_t)z * (DIM * DIM) + (size_t)y * DIM + xx;
                #pragma unroll
                for (int r = 0; r < 4; ++r)
                    out[(size_t)(b * COUT + ob + r) * SP + p] = acc[mt][nt][q * 4 + r] + bv[r];
            }
        }
    }
}

// ---------------------------------------------------------------------------
extern "C" void kernel_launch(void* const* d_in, const int* in_sizes, int n_in,
                              void* d_out, int out_size, void* d_ws, size_t ws_size,
                              hipStream_t stream) {
    const float* x       = (const float*)d_in[0];
    const float* style   = (const float*)d_in[1];
    const float* weight  = (const float*)d_in[2];
    const float* bias    = (const float*)d_in[3];
    const float* w_scale = (const float*)d_in[4];
    const float* b_scale = (const float*)d_in[5];
    const float* w_shift = (const float*)d_in[6];
    const float* b_shift = (const float*)d_in[7];
    const float* w_kmod  = (const float*)d_in[8];
    const float* b_kmod  = (const float*)d_in[9];
    float* out = (float*)d_out;
    float* ws  = (float*)d_ws;

    unsigned short* xpb  = (unsigned short*)((char*)d_ws + XPB_OFF);
    unsigned short* wsbf = (unsigned short*)((char*)d_ws + WSBF_OFF);

    {
        int waves = NB * (2 * CIN + CIN * TAPS);
        int blocks = (waves + 3) / 4;
        modparams_kernel<<<blocks, 256, 0, stream>>>(style, w_scale, b_scale,
                                                     w_shift, b_shift, w_kmod, b_kmod, ws);
    }
    {
        int n = NB * 27 * 8 * 128 * 8;
        build_wsbf2_kernel<<<(n + 255) / 256, 256, 0, stream>>>(weight, ws, wsbf);
    }
    {
        int blocks = NB * 50 * 50;
        pad_kernel<<<blocks, 256, 0, stream>>>(x, ws, xpb);
    }
    {
        int blocks = NB * 432;   // 1728
        conv_fast7_kernel<<<blocks, 512, 0, stream>>>(xpb, wsbf, bias, out);
    }
}

// Round 10
// 236.524 us; speedup vs baseline: 1.5379x; 1.1027x over previous
//
#include <hip/hip_runtime.h>
#include <hip/hip_bf16.h>

// Problem constants
#define NB   4
#define CIN  64
#define COUT 128
#define SDIM 512
#define DIM  48
#define SP   (DIM*DIM*DIM)   // 110592
#define TAPS 27
#define KTOT (CIN*TAPS)      // 1728

// ---- small-param layout (float offsets at base of ws) ----
#define WS_S1P 0                         // [NB*CIN]       1+scale
#define WS_SH  (WS_S1P + NB*CIN)         // [NB*CIN]       shift
#define WS_KM  (WS_SH + NB*CIN)          // [NB*CIN*TAPS]  kmod
// ---- fast path byte offsets ----
#define XPB_OFF   32768ull                        // padded mod x (bf16 channel-last), 64 MB
#define XPB_BYTES (4ull*125000ull*64ull*2ull)     // 64,000,000
#define WSBF_OFF  (XPB_OFF + XPB_BYTES)
#define WSBF_BYTES ((size_t)NB*27*8*128*8*2)      // 1,769,472

typedef __attribute__((ext_vector_type(4))) float  f32x4;
typedef __attribute__((ext_vector_type(8))) short  short8;
typedef __attribute__((ext_vector_type(8))) unsigned short u16x8;

// ---------------------------------------------------------------------------
// Kernel A: style dot products. One wave per row.
// ---------------------------------------------------------------------------
__global__ void modparams_kernel(const float* __restrict__ style,
                                 const float* __restrict__ w_scale, const float* __restrict__ b_scale,
                                 const float* __restrict__ w_shift, const float* __restrict__ b_shift,
                                 const float* __restrict__ w_kmod,  const float* __restrict__ b_kmod,
                                 float* __restrict__ ws) {
    const int ROWS = 2 * CIN + CIN * TAPS;  // 1856
    int gwave = (blockIdx.x * blockDim.x + threadIdx.x) >> 6;
    int lane  = threadIdx.x & 63;
    if (gwave >= NB * ROWS) return;
    int b = gwave / ROWS;
    int r = gwave % ROWS;

    const float* srow = style + b * SDIM;
    const float* mrow;
    float bias, add = 0.f;
    float* dst;
    if (r < CIN) {
        mrow = w_scale + r * SDIM; bias = b_scale[r];
        dst = ws + WS_S1P + b * CIN + r; add = 1.f;          // store (1+scale)
    } else if (r < 2 * CIN) {
        int c = r - CIN;
        mrow = w_shift + c * SDIM; bias = b_shift[c];
        dst = ws + WS_SH + b * CIN + c;
    } else {
        int t = r - 2 * CIN;
        mrow = w_kmod + t * SDIM; bias = b_kmod[t];
        dst = ws + WS_KM + b * (CIN * TAPS) + t;
    }

    float acc = 0.f;
    for (int k = lane; k < SDIM; k += 64) acc += srow[k] * mrow[k];
    #pragma unroll
    for (int off = 32; off; off >>= 1) acc += __shfl_down(acc, off);
    if (lane == 0) *dst = acc + bias + add;
}

// ---------------------------------------------------------------------------
// WSBF2[(((b*27+tau)*8 + s)*128 + o)*8 + j] = bf16(weight[o, c=s*8+j, tau] *
//                                                  (1 + kmod[b, c, tau]))
// ---------------------------------------------------------------------------
__global__ void build_wsbf2_kernel(const float* __restrict__ weight, const float* __restrict__ ws,
                                   unsigned short* __restrict__ wsbf) {
    int d = blockIdx.x * blockDim.x + threadIdx.x;
    if (d >= NB * 27 * 8 * 128 * 8) return;
    int j   = d & 7;
    int o   = (d >> 3) & 127;
    int s   = (d >> 10) & 7;
    int rem = d >> 13;
    int tau = rem % 27;
    int b   = rem / 27;
    int c   = s * 8 + j;
    float wm = weight[(o * CIN + c) * TAPS + tau] * (1.f + ws[WS_KM + b * KTOT + c * TAPS + tau]);
    __hip_bfloat16 h = __float2bfloat16(wm);
    wsbf[d] = *(unsigned short*)&h;
}

// ---------------------------------------------------------------------------
// Pad + modulate + transpose to channel-last bf16: xpb[b][pz][py][px][c]
// ---------------------------------------------------------------------------
__global__ __launch_bounds__(256) void pad_kernel(const float* __restrict__ x,
                                                  const float* __restrict__ ws,
                                                  unsigned short* __restrict__ xpb) {
    __shared__ unsigned short lxm[48 * 72];   // [w][c], row stride 144B (16B-aligned)
    int bid = blockIdx.x;
    int py = bid % 50;
    int pz = (bid / 50) % 50;
    int b  = bid / 2500;
    int t = threadIdx.x;
    bool interior = (pz >= 1 && pz <= 48 && py >= 1 && py <= 48);
    if (interior) {
        int z = pz - 1, y = py - 1;
        const float* xr = x + (size_t)b * CIN * SP + (size_t)z * (DIM*DIM) + y * DIM;
        for (int i = t; i < 3072; i += 256) {
            int c = i / 48, w = i % 48;
            float v = xr[(size_t)c * SP + w];
            float m = v * ws[WS_S1P + b * CIN + c] + ws[WS_SH + b * CIN + c];
            __hip_bfloat16 h = __float2bfloat16(m);
            lxm[w * 72 + c] = *(unsigned short*)&h;
        }
    }
    __syncthreads();
    unsigned short* dst = xpb + (size_t)b * 8000000ull + ((size_t)pz * 2500 + py * 50) * 64;
    for (int i8 = t; i8 < 400; i8 += 256) {
        int w  = i8 >> 3;          // padded px
        int c8 = (i8 & 7) * 8;
        u16x8 v = {};
        if (interior && w >= 1 && w <= 48)
            v = *(const u16x8*)&lxm[(w - 1) * 72 + c8];
        *(u16x8*)(dst + i8 * 8) = v;
    }
}

// ---------------------------------------------------------------------------
// Conv v8: block = 128 couts x 192 positions (3z x 8y x 8x box), 384 thr
// (6 waves: wz 0..2 x mh 0..1). 16x16x32 MFMA, 4x4 frags per wave.
// B halo 5z x 10y x 10x x 64c bf16 in LDS, SLOT-MAJOR [slot(8)][pos(500)]
// with +16B plane pad (64,128 B total -> 2 blocks/CU): B-reads are base-reg +
// compile-time ds offset immediates (zero VALU/tap), conflict-uniform.
// A weights double-buffered in PINNED registers via inline-asm
// global_load_dwordx4 + per-tap s_waitcnt vmcnt(8) + sched_barrier(0).
// ZERO block-wide barriers in the 27-tap loop -> waves free-run.
// ---------------------------------------------------------------------------
#define HALOPOS 500            // 5*10*10
#define PLANE   4008           // shorts per slot plane (500*8 + 8 pad)

#define GLD16R(dst, p, OFF)                                                    \
    asm volatile("global_load_dwordx4 %0, %1, off offset:" #OFF                \
                 : "=v"(dst) : "v"(p) : "memory")

#define ISSUEA(buf, tap_) do {                                                 \
    const unsigned short* _p0 = wA + (size_t)(tap_) * 8192;                    \
    const unsigned short* _p1 = _p0 + 4096;                                    \
    GLD16R(buf[0], _p0, 0);   GLD16R(buf[1], _p0, 256);                        \
    GLD16R(buf[2], _p0, 512); GLD16R(buf[3], _p0, 768);                        \
    GLD16R(buf[4], _p1, 0);   GLD16R(buf[5], _p1, 256);                        \
    GLD16R(buf[6], _p1, 512); GLD16R(buf[7], _p1, 768);                        \
} while (0)

// tap delta within halo position space (compile-time when unrolled)
#define DLT(t_) (((t_) / 9) * 100 + (((t_) / 3) % 3) * 10 + ((t_) % 3))

#define TAPX(cur, nxt, t_) do {                                                \
    short8 bfr0[4], bfr1[4];                                                   \
    _Pragma("unroll")                                                          \
    for (int nf = 0; nf < 4; ++nf)                                             \
        bfr0[nf] = *(const short8*)&Bh[bOff0 + (DLT(t_) + nf * 20) * 8];       \
    if ((t_) < 26) {                                                           \
        ISSUEA(nxt, (t_) + 1);                                                 \
        asm volatile("s_waitcnt vmcnt(8)" ::: "memory");                       \
    } else {                                                                   \
        asm volatile("s_waitcnt vmcnt(0)" ::: "memory");                       \
    }                                                                          \
    __builtin_amdgcn_sched_barrier(0);                                         \
    __builtin_amdgcn_s_setprio(1);                                             \
    _Pragma("unroll")                                                          \
    for (int mf = 0; mf < 4; ++mf)                                             \
        _Pragma("unroll")                                                      \
        for (int nf = 0; nf < 4; ++nf)                                         \
            acc[mf][nf] = __builtin_amdgcn_mfma_f32_16x16x32_bf16(             \
                cur[mf], bfr0[nf], acc[mf][nf], 0, 0, 0);                      \
    __builtin_amdgcn_s_setprio(0);                                             \
    _Pragma("unroll")                                                          \
    for (int nf = 0; nf < 4; ++nf)                                             \
        bfr1[nf] = *(const short8*)&Bh[bOff1 + (DLT(t_) + nf * 20) * 8];       \
    __builtin_amdgcn_s_setprio(1);                                             \
    _Pragma("unroll")                                                          \
    for (int mf = 0; mf < 4; ++mf)                                             \
        _Pragma("unroll")                                                      \
        for (int nf = 0; nf < 4; ++nf)                                         \
            acc[mf][nf] = __builtin_amdgcn_mfma_f32_16x16x32_bf16(             \
                cur[4 + mf], bfr1[nf], acc[mf][nf], 0, 0, 0);                  \
    __builtin_amdgcn_s_setprio(0);                                             \
} while (0)

__global__ __launch_bounds__(384, 3) void conv_fast8_kernel(
    const unsigned short* __restrict__ xpb,
    const unsigned short* __restrict__ wsbf,
    const float* __restrict__ bias,
    float* __restrict__ out)
{
    __shared__ unsigned short Bh[8 * PLANE];   // 64,128 B

    const int t    = threadIdx.x;
    const int lane = t & 63;
    const int wid  = t >> 6;        // 0..5
    const int wz   = wid % 3;       // z-plane
    const int mh   = wid / 3;       // M half (0/1)

    // XCD-aware bijective swizzle: 2304 = 8 * 288
    int bid0 = blockIdx.x;
    int bid  = (bid0 & 7) * 288 + (bid0 >> 3);
    int tile = bid % 576;
    int b    = bid / 576;
    int tx = tile % 6;
    int ty = (tile / 6) % 6;
    int tz = tile / 36;             // 0..15
    int x0 = tx * 8, y0 = ty * 8, z0 = tz * 3;

    const unsigned short* xb = xpb + (size_t)b * 8000000ull;
    const unsigned short* wb = wsbf + (size_t)b * (27 * 8 * 128 * 8);

    const int col  = lane & 15;
    const int krow = lane >> 4;   // 0..3
    const int cy   = col >> 3;    // 0..1
    const int cx   = col & 7;     // 0..7
    const int pbase = wz * 100 + cy * 10 + cx;

    // per-lane B base offsets (shorts): slot-major planes
    const int bOff0 = krow * PLANE + pbase * 8;        // ch0: slot = krow
    const int bOff1 = (4 + krow) * PLANE + pbase * 8;  // ch1: slot = 4+krow

    // per-lane A base (shorts): slot = ch*4 + krow, o = mh*64 + mf*16 + col
    const unsigned short* wA = wb + (size_t)(krow * 128 + mh * 64 + col) * 8;

    f32x4 acc[4][4] = {};
    short8 a0[8], a1[8];

    ISSUEA(a0, 0);   // tap-0 A in flight; drained by the barrier below

    // ---- stage halo: coalesced global reads -> slot-major ds_write scatter
    // chunk i (0..3999): pidx = i>>3, slot = i&7; conflict-free via PLANE pad.
    {
        u16x8 stg[11];
        int   li[11];
        #pragma unroll
        for (int it = 0; it < 11; ++it) {
            int i = it * 384 + t;
            li[it] = i;
            if (i < HALOPOS * 8) {
                int pidx = i >> 3;
                int slot = i & 7;
                int hx = pidx % 10;
                int hy = (pidx / 10) % 10;
                int hz = pidx / 100;
                const unsigned short* g = xb
                    + ((size_t)((z0 + hz) * 2500 + (y0 + hy) * 50 + (x0 + hx))) * 64
                    + slot * 8;
                stg[it] = *(const u16x8*)g;
            }
        }
        #pragma unroll
        for (int it = 0; it < 11; ++it) {
            int i = li[it];
            if (i < HALOPOS * 8) {
                int pidx = i >> 3;
                int slot = i & 7;
                *(u16x8*)&Bh[slot * PLANE + pidx * 8] = stg[it];
            }
        }
    }
    __syncthreads();   // halo staged; the ONLY block-wide barrier

    #pragma unroll
    for (int tap = 0; tap < 27; ++tap) {
        if ((tap & 1) == 0) TAPX(a0, a1, tap);
        else                TAPX(a1, a0, tap);
    }

    // ---- epilogue: + bias, store ----
    int z  = z0 + wz;
    int xx = x0 + cx;
    #pragma unroll
    for (int mf = 0; mf < 4; ++mf) {
        f32x4 bv = *(const f32x4*)&bias[mh * 64 + mf * 16 + krow * 4];
        #pragma unroll
        for (int nf = 0; nf < 4; ++nf) {
            int y = y0 + nf * 2 + cy;
            size_t p = (size_t)z * (DIM * DIM) + (size_t)y * DIM + xx;
            f32x4 a = acc[mf][nf];
            #pragma unroll
            for (int r = 0; r < 4; ++r) {
                int o = mh * 64 + mf * 16 + krow * 4 + r;
                out[(size_t)(b * COUT + o) * SP + p] = a[r] + bv[r];
            }
        }
    }
}

// ---------------------------------------------------------------------------
extern "C" void kernel_launch(void* const* d_in, const int* in_sizes, int n_in,
                              void* d_out, int out_size, void* d_ws, size_t ws_size,
                              hipStream_t stream) {
    const float* x       = (const float*)d_in[0];
    const float* style   = (const float*)d_in[1];
    const float* weight  = (const float*)d_in[2];
    const float* bias    = (const float*)d_in[3];
    const float* w_scale = (const float*)d_in[4];
    const float* b_scale = (const float*)d_in[5];
    const float* w_shift = (const float*)d_in[6];
    const float* b_shift = (const float*)d_in[7];
    const float* w_kmod  = (const float*)d_in[8];
    const float* b_kmod  = (const float*)d_in[9];
    float* out = (float*)d_out;
    float* ws  = (float*)d_ws;

    unsigned short* xpb  = (unsigned short*)((char*)d_ws + XPB_OFF);
    unsigned short* wsbf = (unsigned short*)((char*)d_ws + WSBF_OFF);

    {
        int waves = NB * (2 * CIN + CIN * TAPS);
        int blocks = (waves + 3) / 4;
        modparams_kernel<<<blocks, 256, 0, stream>>>(style, w_scale, b_scale,
                                                     w_shift, b_shift, w_kmod, b_kmod, ws);
    }
    {
        int n = NB * 27 * 8 * 128 * 8;
        build_wsbf2_kernel<<<(n + 255) / 256, 256, 0, stream>>>(weight, ws, wsbf);
    }
    {
        int blocks = NB * 50 * 50;
        pad_kernel<<<blocks, 256, 0, stream>>>(x, ws, xpb);
    }
    {
        int blocks = NB * 576;   // 2304
        conv_fast8_kernel<<<blocks, 384, 0, stream>>>(xpb, wsbf, bias, out);
    }
}